// Round 1
// baseline (227.838 us; speedup 1.0000x reference)
//
#include <hip/hip_runtime.h>

// cumprod along dim 1 of (ROWS, N) fp32, row-major.
// One 256-thread block per row; 3-phase scan through padded LDS.

#define N      8192
#define T      256
#define CHUNK  32              // N / T, elements per thread
#define PADN   (N + (N / 32)) // +1 float of pad per 32 elements -> 8448

__device__ __forceinline__ int pidx(int e) { return e + (e >> 5); }

__global__ __launch_bounds__(T) void cumprod_rows_kernel(
    const float* __restrict__ x, float* __restrict__ out, int n_rows)
{
    __shared__ float lds[PADN];
    __shared__ float wsum[T / 64];

    const int row = blockIdx.x;
    if (row >= n_rows) return;
    const int tid = threadIdx.x;

    const float* __restrict__ xr   = x   + (size_t)row * N;
    float*       __restrict__ outr = out + (size_t)row * N;

    // ---- Phase A: coalesced global -> padded LDS (float4) ----
#pragma unroll
    for (int v = 0; v < N / (T * 4); ++v) {         // 8 iters
        const int e  = (v * T + tid) * 4;           // e % 32 in {0,4,...,28}
        const float4 d = *reinterpret_cast<const float4*>(xr + e);
        const int pe = pidx(e);                     // pe..pe+3 contiguous
        lds[pe + 0] = d.x; lds[pe + 1] = d.y;
        lds[pe + 2] = d.z; lds[pe + 3] = d.w;
    }
    __syncthreads();

    // ---- Phase B: per-thread inclusive scan of its contiguous chunk ----
    // chunk base (padded) = tid*33 -> bank (tid + j) & 31: 2-way only (free)
    const int pbase = tid * (CHUNK + 1);
    float vals[CHUNK];
    float p = 1.0f;
#pragma unroll
    for (int j = 0; j < CHUNK; ++j) {
        p *= lds[pbase + j];
        vals[j] = p;
    }

    // ---- Phase C: block-level exclusive product-scan of chunk totals ----
    const int lane = tid & 63;
    const int wid  = tid >> 6;

    float inc = p;                    // wave inclusive scan (product)
#pragma unroll
    for (int off = 1; off < 64; off <<= 1) {
        const float o = __shfl_up(inc, off, 64);
        if (lane >= off) inc *= o;
    }
    if (lane == 63) wsum[wid] = inc;  // wave totals
    __syncthreads();

    float wpre = 1.0f;                // product of preceding wave totals
    for (int w = 0; w < wid; ++w) wpre *= wsum[w];

    float excl = __shfl_up(inc, 1, 64);
    if (lane == 0) excl = 1.0f;
    excl *= wpre;                     // exclusive prefix for this thread

    // ---- Phase D: apply prefix, write back into padded LDS ----
#pragma unroll
    for (int j = 0; j < CHUNK; ++j) lds[pbase + j] = vals[j] * excl;
    __syncthreads();

    // ---- Phase E: padded LDS -> coalesced global (float4) ----
#pragma unroll
    for (int v = 0; v < N / (T * 4); ++v) {
        const int e  = (v * T + tid) * 4;
        const int pe = pidx(e);
        float4 d;
        d.x = lds[pe + 0]; d.y = lds[pe + 1];
        d.z = lds[pe + 2]; d.w = lds[pe + 3];
        *reinterpret_cast<float4*>(outr + e) = d;
    }
}

extern "C" void kernel_launch(void* const* d_in, const int* in_sizes, int n_in,
                              void* d_out, int out_size, void* d_ws, size_t ws_size,
                              hipStream_t stream)
{
    const float* x   = (const float*)d_in[0];
    float*       out = (float*)d_out;
    const int n_rows = in_sizes[0] / N;   // 4096
    cumprod_rows_kernel<<<n_rows, T, 0, stream>>>(x, out, n_rows);
}